// Round 6
// baseline (323.617 us; speedup 1.0000x reference)
//
#include <hip/hip_runtime.h>

// VectorQuantizer round 6: split-bf16 MFMA with ON-THE-FLY fragment build
// from C in d_in (the only cacheable memory — r1-r5 evidence: d_ws AND d_out
// reads behave uncached, d_in reads hit L2/L3).
//   -2e = ehi+elo (bf16 RNE), c = chi+clo; -2dot ~= ehi@chi + elo@chi + ehi@clo
// MFMA 32x32x16, D[m=codeword][n=enc_row]. A-frag per lane = 2 contiguous
// float4 of C row (lane-natural layout), split in registers each use.
// cnorm computed in-wave from the same loads. No atomics / no pre-zeroing:
// per-block loss slots + ballot-compacted per-block flag lists.
// Rows with observed top-2 gap < MARGIN get exact fp32 rescan in vq_fix
// (covers split-approx error ~6e-6 + 10-bit index-stuffing trunc 1.5e-5).
// Output: [0,N) idx as float | [N,N+N*D) quantized | +0,1,2 = vq,embed,commit.

#define NROWS 65536
#define DIM   128
#define DV    32
#define MSE_DENOM 8388608.0f
#define MARGIN 4.0e-5f

// ws WORD layout: LOSS[1024] floats @0; CNT[512] ints @1024; LIST[512*128] @2048
#define WS_LOSS_F 0
#define WS_CNT_I  1024
#define WS_LIST_I 2048

typedef __attribute__((ext_vector_type(8)))  short short8;
typedef __attribute__((ext_vector_type(16))) float float16v;
typedef __attribute__((ext_vector_type(4)))  float floatx4;
union U4S8 { uint4 u; short8 s; };

__device__ __forceinline__ unsigned bf16rne(float x) {
  unsigned u = __float_as_uint(x);
  return (u + 0x7FFFu + ((u >> 16) & 1u)) >> 16;
}
__device__ __forceinline__ void split2(float y, unsigned& hb, unsigned& lb) {
  hb = bf16rne(y);
  float hf = __uint_as_float(hb << 16);
  lb = bf16rne(y - hf);
}

// ---------------- main: MFMA sweep + argmin + loss + gather ----------------
__global__ __launch_bounds__(256, 2) void vq_main6(const float* __restrict__ E,
                                                   const float* __restrict__ C,
                                                   float* __restrict__ wsf,
                                                   float* __restrict__ out) {
  __shared__ uint4  EH[2048];          // 128 rows x 16 k-chunks, frag-linear (32 KB)
  __shared__ uint4  EL[2048];          // 32 KB
  __shared__ float  PART[256];         // [row][half] partial ||e||^2
  __shared__ float2 M2[512];           // [wave][row] stuffed best/second
  __shared__ int    BI[128];
  __shared__ int    W0CNT;

  const int tid  = threadIdx.x;
  const int w    = tid >> 6;
  const int l    = tid & 63;
  const int half = l >> 5;
  const int rr   = l & 31;
  const int row0 = blockIdx.x * 128;

  // ---- stage E tile: -2e split hi/lo into frag-linear LDS; ||e||^2 partials ----
  {
    int r = w * 32 + rr;
    const float* eb = E + (size_t)(row0 + r) * DIM + half * 64;
    float s2 = 0.f;
#pragma unroll
    for (int i = 0; i < 8; ++i) {
      floatx4 x0 = __builtin_nontemporal_load((const floatx4*)(eb + i * 8));
      floatx4 x1 = __builtin_nontemporal_load((const floatx4*)(eb + i * 8 + 4));
      s2 = fmaf(x0.x, x0.x, s2); s2 = fmaf(x0.y, x0.y, s2);
      s2 = fmaf(x0.z, x0.z, s2); s2 = fmaf(x0.w, x0.w, s2);
      s2 = fmaf(x1.x, x1.x, s2); s2 = fmaf(x1.y, x1.y, s2);
      s2 = fmaf(x1.z, x1.z, s2); s2 = fmaf(x1.w, x1.w, s2);
      unsigned h[8], lo[8];
      split2(-2.f * x0.x, h[0], lo[0]); split2(-2.f * x0.y, h[1], lo[1]);
      split2(-2.f * x0.z, h[2], lo[2]); split2(-2.f * x0.w, h[3], lo[3]);
      split2(-2.f * x1.x, h[4], lo[4]); split2(-2.f * x1.y, h[5], lo[5]);
      split2(-2.f * x1.z, h[6], lo[6]); split2(-2.f * x1.w, h[7], lo[7]);
      int a16 = w * 512 + (half * 8 + i) * 32 + rr;
      EH[a16] = make_uint4(h[0] | (h[1] << 16), h[2] | (h[3] << 16),
                           h[4] | (h[5] << 16), h[6] | (h[7] << 16));
      EL[a16] = make_uint4(lo[0] | (lo[1] << 16), lo[2] | (lo[3] << 16),
                           lo[4] | (lo[5] << 16), lo[6] | (lo[7] << 16));
    }
    PART[r * 2 + half] = s2;
  }
  __syncthreads();

  const float INF = __uint_as_float(0x7F800000u);
  float best[4], sec[4];
#pragma unroll
  for (int n = 0; n < 4; ++n) { best[n] = INF; sec[n] = INF; }

  // ---- sweep: wave w covers mtiles 8w..8w+7; A-frags built from C (cached) ----
  for (int m = 0; m < 8; ++m) {
    const int mt = w * 8 + m;
    const float* cbase = C + ((size_t)(mt * 32 + rr) << 7) + half * 8;
    float16v acc[4];
#pragma unroll
    for (int n = 0; n < 4; ++n)
#pragma unroll
      for (int r2 = 0; r2 < 16; ++r2) acc[n][r2] = 0.f;
    float cs2 = 0.f;

#pragma unroll
    for (int s = 0; s < 8; ++s) {
      floatx4 f0 = *(const floatx4*)(cbase + s * 16);
      floatx4 f1 = *(const floatx4*)(cbase + s * 16 + 4);
      cs2 = fmaf(f0.x, f0.x, cs2); cs2 = fmaf(f0.y, f0.y, cs2);
      cs2 = fmaf(f0.z, f0.z, cs2); cs2 = fmaf(f0.w, f0.w, cs2);
      cs2 = fmaf(f1.x, f1.x, cs2); cs2 = fmaf(f1.y, f1.y, cs2);
      cs2 = fmaf(f1.z, f1.z, cs2); cs2 = fmaf(f1.w, f1.w, cs2);
      unsigned h[8], lo[8];
      split2(f0.x, h[0], lo[0]); split2(f0.y, h[1], lo[1]);
      split2(f0.z, h[2], lo[2]); split2(f0.w, h[3], lo[3]);
      split2(f1.x, h[4], lo[4]); split2(f1.y, h[5], lo[5]);
      split2(f1.z, h[6], lo[6]); split2(f1.w, h[7], lo[7]);
      U4S8 ah, al;
      ah.u = make_uint4(h[0] | (h[1] << 16), h[2] | (h[3] << 16),
                        h[4] | (h[5] << 16), h[6] | (h[7] << 16));
      al.u = make_uint4(lo[0] | (lo[1] << 16), lo[2] | (lo[3] << 16),
                        lo[4] | (lo[5] << 16), lo[6] | (lo[7] << 16));
#pragma unroll
      for (int n = 0; n < 4; ++n) {
        U4S8 bh, bl;
        bh.u = EH[n * 512 + (s * 2 + half) * 32 + rr];
        bl.u = EL[n * 512 + (s * 2 + half) * 32 + rr];
        acc[n] = __builtin_amdgcn_mfma_f32_32x32x16_bf16(ah.s, bh.s, acc[n], 0, 0, 0);
        acc[n] = __builtin_amdgcn_mfma_f32_32x32x16_bf16(al.s, bh.s, acc[n], 0, 0, 0);
        acc[n] = __builtin_amdgcn_mfma_f32_32x32x16_bf16(ah.s, bl.s, acc[n], 0, 0, 0);
      }
    }

    // in-wave cnorm: lane rr & rr+32 partials sum to ||c_{mt*32+rr}||^2
    float cnfull = cs2 + __shfl_xor(cs2, 32);

    // fold: index-stuffed float min/max; cnorm fetched cross-lane per reg
    const unsigned mtb = (unsigned)(mt * 32);
#pragma unroll
    for (int reg = 0; reg < 16; ++reg) {
      const int q = reg >> 2, i2 = reg & 3;
      const int co = half * 4 + q * 8 + i2;            // codeword offset in tile
      const float cnk = __shfl(cnfull, co, 32);
      const unsigned idx = mtb + (unsigned)co;
#pragma unroll
      for (int n = 0; n < 4; ++n) {
        float sc = acc[n][reg] + cnk;
        float uf = __uint_as_float((__float_as_uint(sc) & 0xFFFFFC00u) | idx);
        float nb = fminf(best[n], uf);
        sec[n]  = fminf(sec[n], fmaxf(best[n], uf));
        best[n] = nb;
      }
    }
  }

  // ---- merge halves, stash per-wave results ----
#pragma unroll
  for (int n = 0; n < 4; ++n) {
    float b = best[n], s = sec[n];
    float ob = __shfl_xor(b, 32);
    float os = __shfl_xor(s, 32);
    float nb = fminf(b, ob);
    float ns = fminf(fminf(s, os), fmaxf(b, ob));
    if (half == 0) M2[w * 128 + n * 32 + rr] = make_float2(nb, ns);
  }
  __syncthreads();

  // ---- final per-row (tid<128): merge 4 waves, index, loss partial, flag ----
  int flagged = 0, rowid = 0;
  if (tid < 128) {
    const int r = tid;
    float2 p0 = M2[r];
    float b = p0.x, s = p0.y;
#pragma unroll
    for (int ww = 1; ww < 4; ++ww) {
      float2 p = M2[ww * 128 + r];
      s = fminf(fminf(s, p.y), fmaxf(b, p.x));
      b = fminf(b, p.x);
    }
    int bi = (int)(__float_as_uint(b) & 1023u);
    out[row0 + r] = (float)bi;
    BI[r] = bi;
    flagged = (s - b < MARGIN) ? 1 : 0;
    rowid = row0 + r;
    float term = PART[r * 2] + PART[r * 2 + 1] + b;
#pragma unroll
    for (int off = 32; off > 0; off >>= 1) term += __shfl_down(term, off);
    if (l == 0) wsf[WS_LOSS_F + 2 * blockIdx.x + w] = term;   // unconditional slot
  }
  unsigned long long mask = __ballot(flagged);
  if (tid == 0) W0CNT = (int)__popcll(mask);
  __syncthreads();
  if (flagged) {
    int off = (int)__popcll(mask & ((1ull << l) - 1)) + (w == 1 ? W0CNT : 0);
    ((int*)wsf)[WS_LIST_I + blockIdx.x * 128 + off] = rowid;
  }
  if (tid == 64) ((int*)wsf)[WS_CNT_I + blockIdx.x] = W0CNT + (int)__popcll(mask);

  // ---- gather quantized_st (C rows L2-hot; nontemporal stores) ----
  const floatx4* C4   = (const floatx4*)C;
  floatx4*       out4 = (floatx4*)out;
#pragma unroll
  for (int it = 0; it < 16; ++it) {
    int flat = it * 256 + tid;
    int r = flat >> 5, d4 = flat & 31;
    floatx4 v = C4[(size_t)BI[r] * DV + d4];
    __builtin_nontemporal_store(v, &out4[(NROWS / 4) + (size_t)(row0 + r) * DV + d4]);
  }
}

// ---------------- vq_fix: exact fp32 rescan of flagged rows + scalars ----------------
__global__ __launch_bounds__(256) void vq_fix(const float* __restrict__ E,
                                              const float* __restrict__ C,
                                              float* __restrict__ wsf,
                                              float* __restrict__ out) {
  __shared__ floatx4 eL[32];
  __shared__ float   sv[256];
  __shared__ int     si[256];
  __shared__ int     RES;
  const int tid = threadIdx.x;
  const floatx4* E4 = (const floatx4*)E;
  const floatx4* C4 = (const floatx4*)C;
  floatx4* out4 = (floatx4*)out;

  if (blockIdx.x == 0 && tid < 64) {   // scalar losses: sum 1024 block partials
    float a = 0.f;
#pragma unroll
    for (int i = 0; i < 16; ++i) a += wsf[WS_LOSS_F + tid * 16 + i];
#pragma unroll
    for (int off = 32; off > 0; off >>= 1) a += __shfl_down(a, off);
    if (tid == 0) {
      float mse = a / MSE_DENOM;
      out[NROWS + NROWS * DIM + 0] = 1.25f * mse;
      out[NROWS + NROWS * DIM + 1] = mse;
      out[NROWS + NROWS * DIM + 2] = mse;
    }
  }

  const int cnt = ((const int*)wsf)[WS_CNT_I + blockIdx.x];
  const int* list = (const int*)wsf + WS_LIST_I + blockIdx.x * 128;

  for (int i = 0; i < cnt; ++i) {
    const int r = list[i];
    if (tid < 32) eL[tid] = E4[(size_t)r * DV + tid];
    __syncthreads();
    float bv = 3.0e38f; int bi = 0;
#pragma unroll
    for (int j = 0; j < 4; ++j) {
      int k = j * 256 + tid;
      float d = 0.f, cn2 = 0.f;
#pragma unroll 8
      for (int d4 = 0; d4 < 32; ++d4) {
        floatx4 c = C4[(size_t)k * DV + d4];
        floatx4 e = eL[d4];
        d = fmaf(c.x, e.x, d); d = fmaf(c.y, e.y, d);
        d = fmaf(c.z, e.z, d); d = fmaf(c.w, e.w, d);
        cn2 = fmaf(c.x, c.x, cn2); cn2 = fmaf(c.y, c.y, cn2);
        cn2 = fmaf(c.z, c.z, cn2); cn2 = fmaf(c.w, c.w, cn2);
      }
      float s = fmaf(-2.f, d, cn2);
      if (s < bv || (s == bv && k < bi)) { bv = s; bi = k; }
    }
    sv[tid] = bv; si[tid] = bi;
    __syncthreads();
    if (tid < 64) {
      float v = sv[tid]; int i0 = si[tid];
#pragma unroll
      for (int q = 1; q < 4; ++q) {
        float v2 = sv[tid + q * 64]; int j2 = si[tid + q * 64];
        if (v2 < v || (v2 == v && j2 < i0)) { v = v2; i0 = j2; }
      }
#pragma unroll
      for (int off = 32; off > 0; off >>= 1) {
        float v2 = __shfl_down(v, off); int j2 = __shfl_down(i0, off);
        if (v2 < v || (v2 == v && j2 < i0)) { v = v2; i0 = j2; }
      }
      if (tid == 0) { RES = i0; out[r] = (float)i0; }
    }
    __syncthreads();
    if (tid < 32) out4[(NROWS / 4) + (size_t)r * DV + tid] = C4[(size_t)RES * DV + tid];
    __syncthreads();
  }
}

extern "C" void kernel_launch(void* const* d_in, const int* in_sizes, int n_in,
                              void* d_out, int out_size, void* d_ws, size_t ws_size,
                              hipStream_t stream) {
  const float* E = (const float*)d_in[0];
  const float* C = (const float*)d_in[1];
  float* out = (float*)d_out;
  float* wsf = (float*)d_ws;

  vq_main6<<<NROWS / 128, 256, 0, stream>>>(E, C, wsf, out);
  vq_fix<<<512, 256, 0, stream>>>(E, C, wsf, out);
}

// Round 7
// 224.925 us; speedup vs baseline: 1.4388x; 1.4388x over previous
//
#include <hip/hip_runtime.h>

// VectorQuantizer round 7: R1-proven memory skeleton (cooperative coalesced
// chunk staging -> LDS -> compute) + single-pass fp16 MFMA.
// scores = -2*E@C^T + ||c||^2; argmin_k; gather; mse losses.
// fp16 RNE single pass: differential score err sigma ~6e-6; index-stuffing
// trunc <=8e-6; rows with observed top-2 gap < MARGIN=3e-5 get exact fp32
// rescan in vq_fix. Accumulator is INITIALIZED with cnorm (prep kernel) so
// the fold is 3 VALU/score (and_or, med3, min).
// MFMA 32x32x16 f16, D[m=codeword][n=enc_row]: col=lane&31,
// row=(reg&3)+8*(reg>>2)+4*(lane>>5)  (layout proven by r2-r6 passing).
// Output: [0,N) idx as float | [N,N+N*D) quantized | +0,1,2 = vq,embed,commit.

#define NROWS 65536
#define DIM   128
#define DV    32
#define MSE_DENOM 8388608.0f
#define MARGIN 3.0e-5f

// ws WORD layout
#define WS_CN_F   0        // cnorm[1024] floats
#define WS_LOSS_F 1024     // per-block loss partial [1024]
#define WS_CNT_I  2048     // per-block flag count [1024]
#define WS_LIST_I 3072     // per-block flag lists [1024][64]

typedef _Float16 half8 __attribute__((ext_vector_type(8)));
typedef float float16v __attribute__((ext_vector_type(16)));
typedef float floatx4 __attribute__((ext_vector_type(4)));
union U4H8 { uint4 u; half8 h; };

// ---------------- prep: cnorm -> ws ----------------
__global__ __launch_bounds__(256) void vq_prep(const float* __restrict__ C,
                                               float* __restrict__ wsf) {
  int k = blockIdx.x * 256 + threadIdx.x;   // grid 4x256 = 1024
  const floatx4* c4 = (const floatx4*)C + (size_t)k * DV;
  float s = 0.f;
#pragma unroll 8
  for (int i = 0; i < DV; ++i) {
    floatx4 v = c4[i];
    s = fmaf(v.x, v.x, s); s = fmaf(v.y, v.y, s);
    s = fmaf(v.z, v.z, s); s = fmaf(v.w, v.w, s);
  }
  wsf[WS_CN_F + k] = s;
}

// ---------------- main ----------------
__global__ __launch_bounds__(256, 3) void vq_main7(const float* __restrict__ E,
                                                   const float* __restrict__ C,
                                                   float* __restrict__ wsf,
                                                   float* __restrict__ out) {
  __shared__ uint4  EH[1024];    // 64 E-rows fp16 (-2e), frag-linear swizzled (16 KB)
  __shared__ uint4  CH[1024];    // 64-codeword chunk fp16, frag-linear swizzled (16 KB)
  __shared__ float  CNL[1024];   // cnorm (4 KB)
  __shared__ float  PART2[1024]; // ||e||^2 partials per (row,seg) (4 KB)
  __shared__ float2 M2[128];     // [wave][32 rows] best/second
  __shared__ int    BI[64];

  const int tid  = threadIdx.x;
  const int w    = tid >> 6;
  const int l    = tid & 63;
  const int half = l >> 5;
  const int rr   = l & 31;
  const int row0 = blockIdx.x * 64;
  const int mm   = w >> 1;       // this wave's codeword half of each chunk
  const int nt   = w & 1;        // this wave's E-row tile

  // cnorm -> LDS (one coalesced burst)
  ((floatx4*)CNL)[tid] = ((const floatx4*)(wsf + WS_CN_F))[tid];

  // ---- stage E tile: coalesced 32B/thread reads, fp16(-2e) frag-linear ----
#pragma unroll
  for (int i = 0; i < 4; ++i) {
    int g = i * 256 + tid;
    int row = g >> 4, seg = g & 15;
    const float* p = E + (size_t)(row0 + row) * DIM + seg * 8;
    floatx4 a = *(const floatx4*)p;
    floatx4 b = *(const floatx4*)(p + 4);
    float s2 = 0.f;
    s2 = fmaf(a.x, a.x, s2); s2 = fmaf(a.y, a.y, s2);
    s2 = fmaf(a.z, a.z, s2); s2 = fmaf(a.w, a.w, s2);
    s2 = fmaf(b.x, b.x, s2); s2 = fmaf(b.y, b.y, s2);
    s2 = fmaf(b.z, b.z, s2); s2 = fmaf(b.w, b.w, s2);
    PART2[g] = s2;
    half8 h;
    h[0] = (_Float16)(-2.f * a.x); h[1] = (_Float16)(-2.f * a.y);
    h[2] = (_Float16)(-2.f * a.z); h[3] = (_Float16)(-2.f * a.w);
    h[4] = (_Float16)(-2.f * b.x); h[5] = (_Float16)(-2.f * b.y);
    h[6] = (_Float16)(-2.f * b.z); h[7] = (_Float16)(-2.f * b.w);
    U4H8 u; u.h = h;
    EH[((row >> 5) * 16 + seg) * 32 + ((row & 31) ^ seg)] = u.u;
  }
  __syncthreads();

  const float INF = __uint_as_float(0x7F800000u);
  float best = INF, sec = INF;

  // ---- chunk loop: 16 chunks of 64 codewords ----
  for (int ch = 0; ch < 16; ++ch) {
    // stage C chunk: coalesced 32B/thread, fp16 frag-linear
#pragma unroll
    for (int i = 0; i < 4; ++i) {
      int p2 = i * 256 + tid;
      int cr = p2 >> 4, seg = p2 & 15;
      const float* cp = C + (size_t)(ch * 64 + cr) * DIM + seg * 8;
      floatx4 a = *(const floatx4*)cp;
      floatx4 b = *(const floatx4*)(cp + 4);
      half8 h;
      h[0] = (_Float16)a.x; h[1] = (_Float16)a.y;
      h[2] = (_Float16)a.z; h[3] = (_Float16)a.w;
      h[4] = (_Float16)b.x; h[5] = (_Float16)b.y;
      h[6] = (_Float16)b.z; h[7] = (_Float16)b.w;
      U4H8 u; u.h = h;
      CH[((cr >> 5) * 16 + seg) * 32 + ((cr & 31) ^ seg)] = u.u;
    }
    __syncthreads();

    // acc init = cnorm (so final acc IS the score)
    float16v acc;
#pragma unroll
    for (int q = 0; q < 4; ++q) {
      floatx4 cnv = *(const floatx4*)&CNL[ch * 64 + mm * 32 + half * 4 + q * 8];
      acc[q * 4 + 0] = cnv.x; acc[q * 4 + 1] = cnv.y;
      acc[q * 4 + 2] = cnv.z; acc[q * 4 + 3] = cnv.w;
    }

    // 8 MFMAs: full K=128 for tile (mm, nt)
#pragma unroll
    for (int s = 0; s < 8; ++s) {
      int sh = s * 2 + half;
      U4H8 av, bv;
      av.u = CH[(mm * 16 + sh) * 32 + (rr ^ sh)];
      bv.u = EH[(nt * 16 + sh) * 32 + (rr ^ sh)];
      acc = __builtin_amdgcn_mfma_f32_32x32x16_f16(av.h, bv.h, acc, 0, 0, 0);
    }

    // fold: 3 VALU/score (and_or, med3, min)
    const unsigned kb = (unsigned)(ch * 64 + mm * 32 + half * 4);
#pragma unroll
    for (int reg = 0; reg < 16; ++reg) {
      const unsigned idx = kb + (unsigned)((reg >> 2) * 8 + (reg & 3));
      float uf = __uint_as_float((__float_as_uint(acc[reg]) & 0xFFFFFC00u) | idx);
      sec  = __builtin_amdgcn_fmed3f(sec, best, uf);
      best = fminf(best, uf);
    }
    __syncthreads();
  }

  // ---- merge halves (lanes rr / rr+32 hold same enc row) ----
  {
    float ob = __shfl_xor(best, 32);
    float os = __shfl_xor(sec, 32);
    float nb = fminf(best, ob);
    float ns = fminf(fminf(sec, os), fmaxf(best, ob));
    if (half == 0) M2[w * 32 + rr] = make_float2(nb, ns);
  }
  __syncthreads();

  // ---- per-row: merge the 2 waves covering this row; index, loss, flag ----
  int flagged = 0;
  if (tid < 64) {
    const int r = tid;
    const int n2 = r >> 5, r2 = r & 31;
    float2 pa = M2[n2 * 32 + r2];
    float2 pb = M2[(2 + n2) * 32 + r2];
    float b = fminf(pa.x, pb.x);
    float s = fminf(fminf(pa.y, pb.y), fmaxf(pa.x, pb.x));
    int bi = (int)(__float_as_uint(b) & 1023u);
    out[row0 + r] = (float)bi;
    BI[r] = bi;
    flagged = (s - b < MARGIN) ? 1 : 0;
    float part = 0.f;
#pragma unroll
    for (int q = 0; q < 4; ++q) {
      floatx4 v = *(const floatx4*)&PART2[r * 16 + q * 4];
      part += v.x + v.y + v.z + v.w;
    }
    float term = part + b;
#pragma unroll
    for (int off = 32; off > 0; off >>= 1) term += __shfl_down(term, off);
    if (tid == 0) wsf[WS_LOSS_F + blockIdx.x] = term;
  }
  unsigned long long mask = __ballot(flagged);
  if (tid < 64 && flagged) {
    int off = (int)__popcll(mask & ((1ull << l) - 1));
    ((int*)wsf)[WS_LIST_I + blockIdx.x * 64 + off] = row0 + tid;
  }
  if (tid == 0) ((int*)wsf)[WS_CNT_I + blockIdx.x] = (int)__popcll(mask);
  __syncthreads();

  // ---- gather quantized_st (C rows L2-hot) ----
  const floatx4* C4   = (const floatx4*)C;
  floatx4*       out4 = (floatx4*)out;
#pragma unroll
  for (int it = 0; it < 8; ++it) {
    int flat = it * 256 + tid;
    int r = flat >> 5, d4 = flat & 31;
    out4[(NROWS / 4) + (size_t)(row0 + r) * DV + d4] = C4[(size_t)BI[r] * DV + d4];
  }
}

// ---------------- vq_fix: batched exact rescan + scalars ----------------
__global__ __launch_bounds__(256) void vq_fix(const float* __restrict__ E,
                                              const float* __restrict__ C,
                                              float* __restrict__ wsf,
                                              float* __restrict__ out) {
  __shared__ int     LL[1024];
  __shared__ int     CNTL[16];
  __shared__ int     PREF[17];
  __shared__ floatx4 ELf[16 * 32];   // 8 KB  (16 rows of E)
  __shared__ floatx4 CSf[64 * 32];   // 32 KB (64-codeword chunk)
  __shared__ float   SV[16 * 64];    // 4 KB
  __shared__ int     SI[16 * 64];    // 4 KB
  __shared__ int     RES[16];
  __shared__ float   LRED[4];

  const int tid = threadIdx.x;
  const int j   = blockIdx.x;        // grid 64: covers main-blocks [16j,16j+16)
  const floatx4* E4 = (const floatx4*)E;
  const floatx4* C4 = (const floatx4*)C;
  floatx4* out4 = (floatx4*)out;

  if (j == 0) {   // scalar losses
    float a = wsf[WS_LOSS_F + tid] + wsf[WS_LOSS_F + tid + 256] +
              wsf[WS_LOSS_F + tid + 512] + wsf[WS_LOSS_F + tid + 768];
#pragma unroll
    for (int off = 32; off > 0; off >>= 1) a += __shfl_down(a, off);
    if ((tid & 63) == 0) LRED[tid >> 6] = a;
    __syncthreads();
    if (tid == 0) {
      float mse = (LRED[0] + LRED[1] + LRED[2] + LRED[3]) / MSE_DENOM;
      out[NROWS + NROWS * DIM + 0] = 1.25f * mse;
      out[NROWS + NROWS * DIM + 1] = mse;
      out[NROWS + NROWS * DIM + 2] = mse;
    }
  }

  if (tid < 16) CNTL[tid] = ((const int*)wsf)[WS_CNT_I + j * 16 + tid];
  __syncthreads();
  if (tid == 0) {
    int a = 0;
#pragma unroll
    for (int b = 0; b < 16; ++b) { PREF[b] = a; a += CNTL[b]; }
    PREF[16] = a;
  }
  __syncthreads();
  const int total = PREF[16];
  if (total == 0) return;

  // collect flag list (parallel)
#pragma unroll
  for (int i = 0; i < 4; ++i) {
    int idx = i * 256 + tid;
    int b = idx >> 6, q = idx & 63;
    if (q < CNTL[b]) LL[PREF[b] + q] = ((const int*)wsf)[WS_LIST_I + (j * 16 + b) * 64 + q];
  }
  __syncthreads();

  for (int done = 0; done < total; done += 16) {
    const int nb = min(16, total - done);
    // stage E rows
#pragma unroll
    for (int i = 0; i < 2; ++i) {
      int f = i * 256 + tid;
      int rl = f >> 5, d4 = f & 31;
      if (rl < nb) ELf[rl * 32 + d4] = E4[(size_t)LL[done + rl] * DV + d4];
    }
    const int cw = tid & 63, rg = tid >> 6;
    float bv[4]; int bi4[4];
#pragma unroll
    for (int q = 0; q < 4; ++q) { bv[q] = 3.0e38f; bi4[q] = 0; }

    for (int ch = 0; ch < 16; ++ch) {
      __syncthreads();
#pragma unroll
      for (int i = 0; i < 8; ++i) {
        int f = i * 256 + tid;
        int cr = f >> 5, d4 = f & 31;
        CSf[cr * 32 + d4] = C4[(size_t)(ch * 64 + cr) * DV + d4];
      }
      __syncthreads();
      float cn = 0.f, d0 = 0.f, d1 = 0.f, d2 = 0.f, d3 = 0.f;
#pragma unroll 8
      for (int d4 = 0; d4 < 32; ++d4) {
        floatx4 c = CSf[cw * 32 + d4];
        cn = fmaf(c.x, c.x, cn); cn = fmaf(c.y, c.y, cn);
        cn = fmaf(c.z, c.z, cn); cn = fmaf(c.w, c.w, cn);
        floatx4 e0 = ELf[(rg + 0) * 32 + d4];
        floatx4 e1 = ELf[(rg + 4) * 32 + d4];
        floatx4 e2 = ELf[(rg + 8) * 32 + d4];
        floatx4 e3 = ELf[(rg + 12) * 32 + d4];
        d0 = fmaf(c.x, e0.x, d0); d0 = fmaf(c.y, e0.y, d0);
        d0 = fmaf(c.z, e0.z, d0); d0 = fmaf(c.w, e0.w, d0);
        d1 = fmaf(c.x, e1.x, d1); d1 = fmaf(c.y, e1.y, d1);
        d1 = fmaf(c.z, e1.z, d1); d1 = fmaf(c.w, e1.w, d1);
        d2 = fmaf(c.x, e2.x, d2); d2 = fmaf(c.y, e2.y, d2);
        d2 = fmaf(c.z, e2.z, d2); d2 = fmaf(c.w, e2.w, d2);
        d3 = fmaf(c.x, e3.x, d3); d3 = fmaf(c.y, e3.y, d3);
        d3 = fmaf(c.z, e3.z, d3); d3 = fmaf(c.w, e3.w, d3);
      }
      const int k = ch * 64 + cw;
      float s0 = fmaf(-2.f, d0, cn), s1 = fmaf(-2.f, d1, cn);
      float s2 = fmaf(-2.f, d2, cn), s3 = fmaf(-2.f, d3, cn);
      if (s0 < bv[0]) { bv[0] = s0; bi4[0] = k; }
      if (s1 < bv[1]) { bv[1] = s1; bi4[1] = k; }
      if (s2 < bv[2]) { bv[2] = s2; bi4[2] = k; }
      if (s3 < bv[3]) { bv[3] = s3; bi4[3] = k; }
    }
    __syncthreads();
#pragma unroll
    for (int q = 0; q < 4; ++q) {
      int rl = rg + q * 4;
      if (rl < nb) { SV[rl * 64 + cw] = bv[q]; SI[rl * 64 + cw] = bi4[q]; }
    }
    __syncthreads();
    if (tid < 16 && tid < nb) {
      float v = SV[tid * 64]; int i0 = SI[tid * 64];
      for (int t = 1; t < 64; ++t) {
        float v2 = SV[tid * 64 + t]; int j2 = SI[tid * 64 + t];
        if (v2 < v || (v2 == v && j2 < i0)) { v = v2; i0 = j2; }
      }
      RES[tid] = i0;
      out[LL[done + tid]] = (float)i0;
    }
    __syncthreads();
#pragma unroll
    for (int i = 0; i < 2; ++i) {
      int f = i * 256 + tid;
      int rl = f >> 5, d4 = f & 31;
      if (rl < nb) out4[(NROWS / 4) + (size_t)LL[done + rl] * DV + d4] = C4[(size_t)RES[rl] * DV + d4];
    }
    __syncthreads();
  }
}

extern "C" void kernel_launch(void* const* d_in, const int* in_sizes, int n_in,
                              void* d_out, int out_size, void* d_ws, size_t ws_size,
                              hipStream_t stream) {
  const float* E = (const float*)d_in[0];
  const float* C = (const float*)d_in[1];
  float* out = (float*)d_out;
  float* wsf = (float*)d_ws;

  vq_prep<<<4, 256, 0, stream>>>(C, wsf);
  vq_main7<<<NROWS / 64, 256, 0, stream>>>(E, C, wsf, out);
  vq_fix<<<64, 256, 0, stream>>>(E, C, wsf, out);
}